// Round 9
// baseline (2984.939 us; speedup 1.0000x reference)
//
#include <hip/hip_runtime.h>
#include <hip/hip_fp16.h>
#include <stdint.h>

#define Tdim 1024
#define INdim 256
#define Hdim 256
#define COLS 1024
#define NSLICE 8
#define NGRP 8
#define GB 16          // batches per group (MFMA M)
#define UPB 32         // units per slice
#define CPB 128        // cols per block
#define NTHREADS 512
// hbuf2: [2][NGRP][GB][128] x 8B granules; granule = 2x{f16 h | u16 tag}
#define HBUF2_QW (2 * NGRP * GB * 128)
#define HBUF2_BYTES (HBUF2_QW * 8)         // 262144

typedef _Float16 half8 __attribute__((ext_vector_type(8)));
typedef float f32x4 __attribute__((ext_vector_type(4)));
typedef unsigned long long ull;

__device__ __forceinline__ uint16_t f2h(float f) {
    __half h = __float2half(f);
    return *reinterpret_cast<uint16_t*>(&h);
}
__device__ __forceinline__ uint32_t pk2(float lo, float hi) {
    return (uint32_t)f2h(lo) | ((uint32_t)f2h(hi) << 16);
}
__device__ __forceinline__ float sigm(float v) {
    return __builtin_amdgcn_rcpf(1.f + __expf(-v));
}
__device__ __forceinline__ float tanhfast(float v) {
    float e = __expf(2.f * v);
    return 1.f - 2.f * __builtin_amdgcn_rcpf(e + 1.f);
}
__device__ __forceinline__ size_t gr_idx(int par, int grp, int m, int s16) {
    return ((((size_t)par * NGRP + grp) * GB + m) << 7) | (size_t)s16;
}
__device__ __forceinline__ ull ld_gr(const ull* p) {
    return __hip_atomic_load(p, __ATOMIC_RELAXED, __HIP_MEMORY_SCOPE_AGENT);
}

// MFMA 16x16x32 f16 lane roles (verified r4-r8):
//   A: lane l -> row(m) = l&15, k = (l>>4)*8 + e
//   B: lane l -> col    = l&15 (per-lane W regs), k = (l>>4)*8 + e
//   C/D: lane l, reg r -> row(m) = (l>>4)*4 + r, col = l&15
__global__ __launch_bounds__(NTHREADS, 1) void lstm_main(
    const float* __restrict__ x, const float* __restrict__ h0,
    const float* __restrict__ c0, const float* __restrict__ wx,
    const float* __restrict__ wh, const float* __restrict__ bias,
    float* __restrict__ out, ull* hbuf2)
{
    const int tid   = threadIdx.x;
    const int grp   = blockIdx.x & 7;
    const int slice = blockIdx.x >> 3;
    const int lane  = tid & 63;
    const int wave  = tid >> 6;
    const int cw    = lane & 15;
    const int lhi   = lane >> 4;          // 0..3
    const int cl    = wave * 16 + cw;     // block-local col: (u_local<<2)|g
    const int g     = cl & 3;
    const int ul    = cl >> 2;            // 0..31
    const int u     = slice * UPB + ul;
    const int gcol  = g * Hdim + u;

    // 128 KB arena: Wl (prologue only), then Hs2[2] (16 KB) aliased on top.
    __shared__ __align__(16) char smem[CPB * 512 * 2];
    uint16_t* Wl = reinterpret_cast<uint16_t*>(smem);
    typedef uint16_t HsT[GB][32][8];
    HsT* Hs2 = reinterpret_cast<HsT*>(smem);             // Hs2[0], Hs2[1]
    __shared__ __align__(16) uint16_t X[2][GB][32][8];   // 16 KB, slot=ko^(m&7)

    // ---------- prologue ----------
    for (int idx = tid; idx < CPB * 512; idx += NTHREADS) {
        int k  = idx >> 7;
        int ci = idx & 127;
        int uu = ci & 31, gg = ci >> 5;
        int cg = gg * Hdim + slice * UPB + uu;          // global col (coalesced over uu)
        int c  = (uu << 2) | gg;                        // block-local col
        float w = (k < INdim) ? wx[(size_t)k * COLS + cg]
                              : wh[(size_t)(k - INdim) * COLS + cg];
        int e = c * 512 + ((((k >> 3) ^ (c & 7)) << 3) | (k & 7));
        Wl[e] = f2h(w);
    }
    const int m_s   = tid >> 5;           // staging row (batch)
    const int ko_s  = tid & 31;           // staging k-oct
    const int slt_s = ko_s ^ (m_s & 7);   // swizzled slot for staging writes
    {   // stage x_0 (conflict-free b128 write)
        const float4* xs = reinterpret_cast<const float4*>(
            &x[((size_t)(grp * GB + m_s) * Tdim + 0) * INdim + ko_s * 8]);
        float4 a = xs[0], b = xs[1];
        uint4 pkv = {pk2(a.x, a.y), pk2(a.z, a.w), pk2(b.x, b.y), pk2(b.z, b.w)};
        *reinterpret_cast<uint4*>(&X[0][m_s][slt_s][0]) = pkv;
    }
    float4 xp0, xp1;  // prefetch x_1
    {
        const float4* xs = reinterpret_cast<const float4*>(
            &x[((size_t)(grp * GB + m_s) * Tdim + 1) * INdim + ko_s * 8]);
        xp0 = xs[0]; xp1 = xs[1];
    }
    // publish h0 granules, tag = 1
    if (tid < 256) {
        int m = tid >> 4, j = tid & 15;
        int u0 = slice * UPB + 2 * j;
        float a = h0[(size_t)(grp * GB + m) * Hdim + u0];
        float b = h0[(size_t)(grp * GB + m) * Hdim + u0 + 1];
        ull v = (ull)(((uint32_t)f2h(a) << 16) | 1u)
              | ((ull)(((uint32_t)f2h(b) << 16) | 1u) << 32);
        __hip_atomic_store(&hbuf2[gr_idx(0, grp, m, slice * 16 + j)], v,
                           __ATOMIC_RELAXED, __HIP_MEMORY_SCOPE_AGENT);
    }
    float c_reg[4];
    #pragma unroll
    for (int r = 0; r < 4; ++r)
        c_reg[r] = c0[(size_t)(grp * GB + lhi * 4 + r) * Hdim + u];
    const float bv = bias[gcol];
    __syncthreads();                      // Wl + X[0] staged

    // W fragments -> registers (Wl dead afterwards; Hs2 aliases it)
    const uint32_t swz = (uint32_t)(cl & 7);
    const uint16_t* wrow = &Wl[cl * 512];
    half8 Wf[16];
    #pragma unroll
    for (int i = 0; i < 16; ++i)
        Wf[i] = *reinterpret_cast<const half8*>(&wrow[(((uint32_t)(i * 4 + lhi)) ^ swz) << 3]);
    __syncthreads();                      // all Wf ds_reads done before Hs2 writes

    const int swz_a = cw & 7;             // A-read slot xor (row = cw)
    const bool pub = (g == 0) && ((ul & 1) == 0);   // cw in {0,8}
    const int s16_pub = slice * 16 + (ul >> 1);
    float hv[4] = {0.f, 0.f, 0.f, 0.f};

    // ---------- time loop: ONE barrier per step ----------
    for (int t = 0; t < Tdim; ++t) {
        const int par = t & 1, pn = par ^ 1;

        // stage x_{t+1} from regs (1 iter of slack; ordered vs readers by the barrier)
        {
            uint4 pkv = {pk2(xp0.x, xp0.y), pk2(xp0.z, xp0.w),
                         pk2(xp1.x, xp1.y), pk2(xp1.z, xp1.w)};
            *reinterpret_cast<uint4*>(&X[pn][m_s][slt_s][0]) = pkv;
        }
        {   // issue prefetch of x_{t+2}
            int tn = (t + 2 < Tdim) ? t + 2 : Tdim - 1;
            const float4* xs = reinterpret_cast<const float4*>(
                &x[((size_t)(grp * GB + m_s) * Tdim + tn) * INdim + ko_s * 8]);
            xp0 = xs[0]; xp1 = xs[1];
        }

        // issue h(t) granule loads (checked after x-GEMM -> latency hidden)
        const uint32_t tt = (uint32_t)(t + 1);
        const ull* gp = hbuf2 + gr_idx(par, grp, m_s, ko_s * 4);
        ull q0 = ld_gr(gp), q1 = ld_gr(gp + 1), q2 = ld_gr(gp + 2), q3 = ld_gr(gp + 3);

        // x-part GEMM (k 0..255) — independent of h(t)
        f32x4 acc0 = {0.f, 0.f, 0.f, 0.f}, acc1 = {0.f, 0.f, 0.f, 0.f};
        #pragma unroll
        for (int s = 0; s < 8; s += 2) {
            int ko0 = s * 4 + lhi, ko1 = ko0 + 4;
            half8 a0 = *reinterpret_cast<const half8*>(&X[par][cw][ko0 ^ swz_a][0]);
            acc0 = __builtin_amdgcn_mfma_f32_16x16x32_f16(a0, Wf[s], acc0, 0, 0, 0);
            half8 a1 = *reinterpret_cast<const half8*>(&X[par][cw][ko1 ^ swz_a][0]);
            acc1 = __builtin_amdgcn_mfma_f32_16x16x32_f16(a1, Wf[s + 1], acc1, 0, 0, 0);
        }

        // poll: every 4B word self-tagged with t+1
        for (;;) {
            ull d = ((q0 ^ tt) | ((q0 >> 32) ^ tt) | (q1 ^ tt) | ((q1 >> 32) ^ tt)
                   | (q2 ^ tt) | ((q2 >> 32) ^ tt) | (q3 ^ tt) | ((q3 >> 32) ^ tt));
            if (((uint32_t)d & 0xFFFFu) == 0) break;
            q0 = ld_gr(gp); q1 = ld_gr(gp + 1); q2 = ld_gr(gp + 2); q3 = ld_gr(gp + 3);
        }
        {   // extract 8 h f16 -> one b128 Hs2 write
            uint4 hw = {(uint32_t)((q0 >> 16) & 0xFFFF) | ((uint32_t)(q0 >> 48) << 16),
                        (uint32_t)((q1 >> 16) & 0xFFFF) | ((uint32_t)(q1 >> 48) << 16),
                        (uint32_t)((q2 >> 16) & 0xFFFF) | ((uint32_t)(q2 >> 48) << 16),
                        (uint32_t)((q3 >> 16) & 0xFFFF) | ((uint32_t)(q3 >> 48) << 16)};
            *reinterpret_cast<uint4*>(&Hs2[par][m_s][slt_s][0]) = hw;
        }
        __syncthreads();   // Hs2[par] staged; also orders X/Hs2 buffer rotation

        // h-part GEMM (k 256..511)
        #pragma unroll
        for (int s = 0; s < 8; s += 2) {
            int ko0 = s * 4 + lhi, ko1 = ko0 + 4;
            half8 a0 = *reinterpret_cast<const half8*>(&Hs2[par][cw][ko0 ^ swz_a][0]);
            acc0 = __builtin_amdgcn_mfma_f32_16x16x32_f16(a0, Wf[8 + s], acc0, 0, 0, 0);
            half8 a1 = *reinterpret_cast<const half8*>(&Hs2[par][cw][ko1 ^ swz_a][0]);
            acc1 = __builtin_amdgcn_mfma_f32_16x16x32_f16(a1, Wf[9 + s], acc1, 0, 0, 0);
        }

        // gates + state update (4 rows per lane)
        #pragma unroll
        for (int r = 0; r < 4; ++r) {
            float tval = acc0[r] + acc1[r] + bv;
            float act = (g == 3) ? tanhfast(tval) : sigm(tval);
            float x1  = __shfl_xor(act, 1);
            float e0  = (g & 1) ? x1 : act;
            float o1  = (g & 1) ? act : x1;
            float e0s = __shfl_xor(e0, 2);
            float o1s = __shfl_xor(o1, 2);
            float f_ = (g < 2) ? e0  : e0s;
            float i_ = (g < 2) ? o1  : o1s;
            float o_ = (g < 2) ? e0s : e0;
            float g_ = (g < 2) ? o1s : o1;
            c_reg[r] = fmaf(c_reg[r], f_, g_ * i_);
            hv[r] = tanhfast(c_reg[r]) * o_;
        }

        // pair units (ul, ul+1) via shfl; publish + fullh straight from regs.
        float hp[4];
        #pragma unroll
        for (int r = 0; r < 4; ++r) hp[r] = __shfl_xor(hv[r], 4);
        if (pub) {
            const uint32_t tg = (uint32_t)(t + 2);
            #pragma unroll
            for (int r = 0; r < 4; ++r) {
                int m = lhi * 4 + r;
                ull v = (ull)(((uint32_t)f2h(hv[r]) << 16) | tg)
                      | ((ull)(((uint32_t)f2h(hp[r]) << 16) | tg) << 32);
                __hip_atomic_store(&hbuf2[gr_idx(pn, grp, m, s16_pub)], v,
                                   __ATOMIC_RELAXED, __HIP_MEMORY_SCOPE_AGENT);
                float2 o2 = {hv[r], hp[r]};
                *reinterpret_cast<float2*>(
                    &out[((size_t)(grp * GB + m) * Tdim + t) * Hdim + u]) = o2;
            }
        }
        // no post-publish barrier: fire-and-forget; readers self-synchronize on tags
    }

    // final h_f, c_f
    if (g == 0) {
        const size_t fsz = (size_t)(NGRP * GB) * Tdim * Hdim;
        #pragma unroll
        for (int r = 0; r < 4; ++r) {
            int m = lhi * 4 + r;
            out[fsz + (size_t)(grp * GB + m) * Hdim + u] = hv[r];
            out[fsz + (size_t)(NGRP * GB) * Hdim + (size_t)(grp * GB + m) * Hdim + u] = c_reg[r];
        }
    }
}

extern "C" void kernel_launch(void* const* d_in, const int* in_sizes, int n_in,
                              void* d_out, int out_size, void* d_ws, size_t ws_size,
                              hipStream_t stream) {
    const float* x    = (const float*)d_in[0];
    const float* h0   = (const float*)d_in[1];
    const float* c0   = (const float*)d_in[2];
    const float* wx   = (const float*)d_in[3];
    const float* wh   = (const float*)d_in[4];
    const float* bias = (const float*)d_in[5];
    float* out = (float*)d_out;
    ull* hbuf2 = (ull*)d_ws;

    // zero all tags every launch (graph-captured): replay-safe, deadlock-safe
    hipMemsetAsync(hbuf2, 0, HBUF2_BYTES, stream);

    void* args[] = {(void*)&x, (void*)&h0, (void*)&c0, (void*)&wx, (void*)&wh,
                    (void*)&bias, (void*)&out, (void*)&hbuf2};
    hipLaunchCooperativeKernel((const void*)lstm_main, dim3(NSLICE * NGRP),
                               dim3(NTHREADS), args, 0, stream);
}